// Round 1
// baseline (155.737 us; speedup 1.0000x reference)
//
#include <hip/hip_runtime.h>
#include <math.h>

// Problem geometry (fixed by the reference): (4,16,4000,400) fp32
#define PLANE_ELEMS 1600000            // 4000*400, per (batch,shot) plane
#define NPLANES     64                 // 4*16
#define BPP         32                 // blocks per plane
#define THREADS     256                // threads per block (4 waves)

// Stage 1: per-plane raw moments in fp64.
// ws layout: ws[plane*5 + {0:S_syn, 1:S_obs, 2:S_ss, 3:S_oo, 4:S_so}]
__global__ __launch_bounds__(THREADS)
void fwi_partials(const float* __restrict__ syn,
                  const float* __restrict__ obs,
                  double* __restrict__ ws)
{
    const int plane = blockIdx.x / BPP;
    const int bip   = blockIdx.x % BPP;
    const int n4    = PLANE_ELEMS / 4;           // 400000 float4 per plane

    const float4* s4 = reinterpret_cast<const float4*>(syn) + (size_t)plane * n4;
    const float4* o4 = reinterpret_cast<const float4*>(obs) + (size_t)plane * n4;

    double s_s = 0.0, s_o = 0.0, s_ss = 0.0, s_oo = 0.0, s_so = 0.0;

    #pragma unroll 2
    for (int i = bip * THREADS + threadIdx.x; i < n4; i += BPP * THREADS) {
        float4 a = s4[i];
        float4 b = o4[i];
        double a0 = a.x, a1 = a.y, a2 = a.z, a3 = a.w;
        double b0 = b.x, b1 = b.y, b2 = b.z, b3 = b.w;

        s_s += (a0 + a1) + (a2 + a3);
        s_o += (b0 + b1) + (b2 + b3);
        s_ss = fma(a0, a0, s_ss); s_ss = fma(a1, a1, s_ss);
        s_ss = fma(a2, a2, s_ss); s_ss = fma(a3, a3, s_ss);
        s_oo = fma(b0, b0, s_oo); s_oo = fma(b1, b1, s_oo);
        s_oo = fma(b2, b2, s_oo); s_oo = fma(b3, b3, s_oo);
        s_so = fma(a0, b0, s_so); s_so = fma(a1, b1, s_so);
        s_so = fma(a2, b2, s_so); s_so = fma(a3, b3, s_so);
    }

    // Wave(64)-level butterfly reduction in fp64
    #pragma unroll
    for (int off = 32; off > 0; off >>= 1) {
        s_s  += __shfl_down(s_s,  off);
        s_o  += __shfl_down(s_o,  off);
        s_ss += __shfl_down(s_ss, off);
        s_oo += __shfl_down(s_oo, off);
        s_so += __shfl_down(s_so, off);
    }

    __shared__ double sm[THREADS / 64][5];
    const int wave = threadIdx.x >> 6;
    const int lane = threadIdx.x & 63;
    if (lane == 0) {
        sm[wave][0] = s_s;  sm[wave][1] = s_o;
        sm[wave][2] = s_ss; sm[wave][3] = s_oo; sm[wave][4] = s_so;
    }
    __syncthreads();

    if (threadIdx.x == 0) {
        double t0 = 0, t1 = 0, t2 = 0, t3 = 0, t4 = 0;
        #pragma unroll
        for (int w = 0; w < THREADS / 64; ++w) {
            t0 += sm[w][0]; t1 += sm[w][1]; t2 += sm[w][2];
            t3 += sm[w][3]; t4 += sm[w][4];
        }
        atomicAdd(&ws[plane * 5 + 0], t0);
        atomicAdd(&ws[plane * 5 + 1], t1);
        atomicAdd(&ws[plane * 5 + 2], t2);
        atomicAdd(&ws[plane * 5 + 3], t3);
        atomicAdd(&ws[plane * 5 + 4], t4);
    }
}

// Stage 2: one wave, one lane per plane. Closed-form zero-mean correlation.
__global__ __launch_bounds__(64)
void fwi_final(const double* __restrict__ ws, float* __restrict__ out)
{
    const double N = (double)PLANE_ELEMS;
    const int p = threadIdx.x;           // 0..63 planes

    double Ss  = ws[p * 5 + 0];
    double So  = ws[p * 5 + 1];
    double Sss = ws[p * 5 + 2];
    double Soo = ws[p * 5 + 3];
    double Sso = ws[p * 5 + 4];

    double cross = Sso - Ss * So / N;
    double Ep    = Sss - Ss * Ss / N;
    double Et    = Soo - So * So / N;
    double term  = cross / (sqrt(Et) * sqrt(Ep));

    #pragma unroll
    for (int off = 32; off > 0; off >>= 1)
        term += __shfl_down(term, off);

    if (p == 0)
        out[0] = (float)(-term);
}

extern "C" void kernel_launch(void* const* d_in, const int* in_sizes, int n_in,
                              void* d_out, int out_size, void* d_ws, size_t ws_size,
                              hipStream_t stream)
{
    const float* syn = (const float*)d_in[0];
    const float* obs = (const float*)d_in[1];
    float* out       = (float*)d_out;
    double* ws       = (double*)d_ws;

    // Zero the 64*5 fp64 accumulator slots (graph-capture safe).
    hipMemsetAsync(ws, 0, NPLANES * 5 * sizeof(double), stream);

    fwi_partials<<<NPLANES * BPP, THREADS, 0, stream>>>(syn, obs, ws);
    fwi_final<<<1, 64, 0, stream>>>(ws, out);
}

// Round 2
// 151.689 us; speedup vs baseline: 1.0267x; 1.0267x over previous
//
#include <hip/hip_runtime.h>
#include <math.h>

// Problem geometry (fixed by the reference): (4,16,4000,400) fp32
#define PLANE_ELEMS 1600000            // 4000*400 per (batch,shot) plane
#define NPLANES     64                 // 4*16
#define BPP         32                 // blocks per plane
#define THREADS     256                // threads per block (4 waves)
#define N4          (PLANE_ELEMS / 4)  // 400000 float4 per plane
#define CHUNK       (N4 / BPP)         // 12500 float4 per block (contiguous)

// Stage 1: per-plane raw moments in fp64, one private slot per block
// (no atomics, no zero-init required).
// ws layout: ws[(plane*BPP + bip)*5 + {0:S_s, 1:S_o, 2:S_ss, 3:S_oo, 4:S_so}]
__global__ __launch_bounds__(THREADS)
void fwi_partials(const float* __restrict__ syn,
                  const float* __restrict__ obs,
                  double* __restrict__ ws)
{
    const int plane = blockIdx.x >> 5;      // / BPP
    const int bip   = blockIdx.x & (BPP - 1);

    const float4* s4 = reinterpret_cast<const float4*>(syn)
                       + (size_t)plane * N4 + (size_t)bip * CHUNK;
    const float4* o4 = reinterpret_cast<const float4*>(obs)
                       + (size_t)plane * N4 + (size_t)bip * CHUNK;

    double s_s = 0.0, s_o = 0.0, s_ss = 0.0, s_oo = 0.0, s_so = 0.0;

    #pragma unroll 4
    for (int i = threadIdx.x; i < CHUNK; i += THREADS) {
        float4 a = s4[i];
        float4 b = o4[i];
        double a0 = a.x, a1 = a.y, a2 = a.z, a3 = a.w;
        double b0 = b.x, b1 = b.y, b2 = b.z, b3 = b.w;

        s_s += (a0 + a1) + (a2 + a3);
        s_o += (b0 + b1) + (b2 + b3);
        s_ss = fma(a0, a0, s_ss); s_ss = fma(a1, a1, s_ss);
        s_ss = fma(a2, a2, s_ss); s_ss = fma(a3, a3, s_ss);
        s_oo = fma(b0, b0, s_oo); s_oo = fma(b1, b1, s_oo);
        s_oo = fma(b2, b2, s_oo); s_oo = fma(b3, b3, s_oo);
        s_so = fma(a0, b0, s_so); s_so = fma(a1, b1, s_so);
        s_so = fma(a2, b2, s_so); s_so = fma(a3, b3, s_so);
    }

    // Wave(64)-level butterfly reduction in fp64
    #pragma unroll
    for (int off = 32; off > 0; off >>= 1) {
        s_s  += __shfl_down(s_s,  off);
        s_o  += __shfl_down(s_o,  off);
        s_ss += __shfl_down(s_ss, off);
        s_oo += __shfl_down(s_oo, off);
        s_so += __shfl_down(s_so, off);
    }

    __shared__ double sm[THREADS / 64][5];
    const int wave = threadIdx.x >> 6;
    const int lane = threadIdx.x & 63;
    if (lane == 0) {
        sm[wave][0] = s_s;  sm[wave][1] = s_o;
        sm[wave][2] = s_ss; sm[wave][3] = s_oo; sm[wave][4] = s_so;
    }
    __syncthreads();

    if (threadIdx.x == 0) {
        double t0 = 0, t1 = 0, t2 = 0, t3 = 0, t4 = 0;
        #pragma unroll
        for (int w = 0; w < THREADS / 64; ++w) {
            t0 += sm[w][0]; t1 += sm[w][1]; t2 += sm[w][2];
            t3 += sm[w][3]; t4 += sm[w][4];
        }
        double* r = ws + (size_t)blockIdx.x * 5;
        r[0] = t0; r[1] = t1; r[2] = t2; r[3] = t3; r[4] = t4;
    }
}

// Stage 2: one block of 256 threads reduces 64 planes x 32 partial records,
// computes the closed-form zero-mean correlation per plane, sums across planes.
__global__ __launch_bounds__(256)
void fwi_final(const double* __restrict__ ws, float* __restrict__ out)
{
    const int t = threadIdx.x;
    const int p = t & 63;        // plane
    const int q = t >> 6;        // quarter 0..3 (8 records each)

    double acc0 = 0, acc1 = 0, acc2 = 0, acc3 = 0, acc4 = 0;
    #pragma unroll
    for (int b = 0; b < BPP / 4; ++b) {
        const double* r = ws + (size_t)((p * BPP) + (q * (BPP / 4)) + b) * 5;
        acc0 += r[0]; acc1 += r[1]; acc2 += r[2]; acc3 += r[3]; acc4 += r[4];
    }

    __shared__ double sm[4][64][5];
    sm[q][p][0] = acc0; sm[q][p][1] = acc1; sm[q][p][2] = acc2;
    sm[q][p][3] = acc3; sm[q][p][4] = acc4;
    __syncthreads();

    if (t < 64) {
        double Ss = 0, So = 0, Sss = 0, Soo = 0, Sso = 0;
        #pragma unroll
        for (int qq = 0; qq < 4; ++qq) {
            Ss  += sm[qq][p][0];
            So  += sm[qq][p][1];
            Sss += sm[qq][p][2];
            Soo += sm[qq][p][3];
            Sso += sm[qq][p][4];
        }
        const double N = (double)PLANE_ELEMS;
        double cross = Sso - Ss * So / N;
        double Ep    = Sss - Ss * Ss / N;
        double Et    = Soo - So * So / N;
        double term  = cross / (sqrt(Et) * sqrt(Ep));

        #pragma unroll
        for (int off = 32; off > 0; off >>= 1)
            term += __shfl_down(term, off);

        if (p == 0)
            out[0] = (float)(-term);
    }
}

extern "C" void kernel_launch(void* const* d_in, const int* in_sizes, int n_in,
                              void* d_out, int out_size, void* d_ws, size_t ws_size,
                              hipStream_t stream)
{
    const float* syn = (const float*)d_in[0];
    const float* obs = (const float*)d_in[1];
    float* out       = (float*)d_out;
    double* ws       = (double*)d_ws;

    fwi_partials<<<NPLANES * BPP, THREADS, 0, stream>>>(syn, obs, ws);
    fwi_final<<<1, 256, 0, stream>>>(ws, out);
}

// Round 3
// 135.830 us; speedup vs baseline: 1.1466x; 1.1168x over previous
//
#include <hip/hip_runtime.h>
#include <math.h>

// Problem geometry (fixed by the reference): (4,16,4000,400) fp32
#define PLANE_ELEMS 1600000            // 4000*400 per (batch,shot) plane
#define NPLANES     64                 // 4*16
#define BPP         32                 // blocks per plane
#define THREADS     256                // threads per block (4 waves)
#define N4          (PLANE_ELEMS / 4)  // 400000 float4 per plane
#define CHUNK       (N4 / BPP)         // 12500 float4 per block (contiguous)
#define BATCH       8                  // vec4-iters per f32 micro-batch
#define NBATCH      (CHUNK / (THREADS * BATCH))   // 6 full batches
#define TAILBASE    (NBATCH * THREADS * BATCH)    // 12288

typedef float f32x4 __attribute__((ext_vector_type(4)));

// Stage 1: per-plane raw moments. f32 micro-batch accumulation (32 pairs)
// flushed into fp64 accumulators; nontemporal streaming loads.
// ws layout: ws[(plane*BPP + bip)*5 + {0:S_s, 1:S_o, 2:S_ss, 3:S_oo, 4:S_so}]
__global__ __launch_bounds__(THREADS)
void fwi_partials(const float* __restrict__ syn,
                  const float* __restrict__ obs,
                  double* __restrict__ ws)
{
    const int plane = blockIdx.x >> 5;      // / BPP
    const int bip   = blockIdx.x & (BPP - 1);

    const f32x4* s4 = reinterpret_cast<const f32x4*>(syn)
                      + (size_t)plane * N4 + (size_t)bip * CHUNK;
    const f32x4* o4 = reinterpret_cast<const f32x4*>(obs)
                      + (size_t)plane * N4 + (size_t)bip * CHUNK;

    double d_s = 0.0, d_o = 0.0, d_ss = 0.0, d_oo = 0.0, d_so = 0.0;

    int i = threadIdx.x;
    for (int b = 0; b < NBATCH; ++b) {
        float fs = 0.f, fo = 0.f, fss = 0.f, foo = 0.f, fso = 0.f;
        #pragma unroll
        for (int u = 0; u < BATCH; ++u) {
            f32x4 a  = __builtin_nontemporal_load(s4 + i + u * THREADS);
            f32x4 bb = __builtin_nontemporal_load(o4 + i + u * THREADS);
            fs  += (a.x + a.y) + (a.z + a.w);
            fo  += (bb.x + bb.y) + (bb.z + bb.w);
            fss = fmaf(a.x, a.x, fss);   fss = fmaf(a.y, a.y, fss);
            fss = fmaf(a.z, a.z, fss);   fss = fmaf(a.w, a.w, fss);
            foo = fmaf(bb.x, bb.x, foo); foo = fmaf(bb.y, bb.y, foo);
            foo = fmaf(bb.z, bb.z, foo); foo = fmaf(bb.w, bb.w, foo);
            fso = fmaf(a.x, bb.x, fso);  fso = fmaf(a.y, bb.y, fso);
            fso = fmaf(a.z, bb.z, fso);  fso = fmaf(a.w, bb.w, fso);
        }
        d_s  += (double)fs;  d_o  += (double)fo;
        d_ss += (double)fss; d_oo += (double)foo; d_so += (double)fso;
        i += THREADS * BATCH;
    }

    // Tail: CHUNK = 12500 = 6*2048 + 212; threads with tid < 212 do one more.
    i = TAILBASE + threadIdx.x;
    if (i < CHUNK) {
        f32x4 a  = __builtin_nontemporal_load(s4 + i);
        f32x4 bb = __builtin_nontemporal_load(o4 + i);
        float fs  = (a.x + a.y) + (a.z + a.w);
        float fo  = (bb.x + bb.y) + (bb.z + bb.w);
        float fss = fmaf(a.x, a.x, fmaf(a.y, a.y, fmaf(a.z, a.z, a.w * a.w)));
        float foo = fmaf(bb.x, bb.x, fmaf(bb.y, bb.y, fmaf(bb.z, bb.z, bb.w * bb.w)));
        float fso = fmaf(a.x, bb.x, fmaf(a.y, bb.y, fmaf(a.z, bb.z, a.w * bb.w)));
        d_s  += (double)fs;  d_o  += (double)fo;
        d_ss += (double)fss; d_oo += (double)foo; d_so += (double)fso;
    }

    // Wave(64)-level butterfly reduction in fp64
    #pragma unroll
    for (int off = 32; off > 0; off >>= 1) {
        d_s  += __shfl_down(d_s,  off);
        d_o  += __shfl_down(d_o,  off);
        d_ss += __shfl_down(d_ss, off);
        d_oo += __shfl_down(d_oo, off);
        d_so += __shfl_down(d_so, off);
    }

    __shared__ double sm[THREADS / 64][5];
    const int wave = threadIdx.x >> 6;
    const int lane = threadIdx.x & 63;
    if (lane == 0) {
        sm[wave][0] = d_s;  sm[wave][1] = d_o;
        sm[wave][2] = d_ss; sm[wave][3] = d_oo; sm[wave][4] = d_so;
    }
    __syncthreads();

    if (threadIdx.x == 0) {
        double t0 = 0, t1 = 0, t2 = 0, t3 = 0, t4 = 0;
        #pragma unroll
        for (int w = 0; w < THREADS / 64; ++w) {
            t0 += sm[w][0]; t1 += sm[w][1]; t2 += sm[w][2];
            t3 += sm[w][3]; t4 += sm[w][4];
        }
        double* r = ws + (size_t)blockIdx.x * 5;
        r[0] = t0; r[1] = t1; r[2] = t2; r[3] = t3; r[4] = t4;
    }
}

// Stage 2: one block of 256 threads reduces 64 planes x 32 partial records,
// computes the closed-form zero-mean correlation per plane, sums across planes.
__global__ __launch_bounds__(256)
void fwi_final(const double* __restrict__ ws, float* __restrict__ out)
{
    const int t = threadIdx.x;
    const int p = t & 63;        // plane
    const int q = t >> 6;        // quarter 0..3 (8 records each)

    double acc0 = 0, acc1 = 0, acc2 = 0, acc3 = 0, acc4 = 0;
    #pragma unroll
    for (int b = 0; b < BPP / 4; ++b) {
        const double* r = ws + (size_t)((p * BPP) + (q * (BPP / 4)) + b) * 5;
        acc0 += r[0]; acc1 += r[1]; acc2 += r[2]; acc3 += r[3]; acc4 += r[4];
    }

    __shared__ double sm[4][64][5];
    sm[q][p][0] = acc0; sm[q][p][1] = acc1; sm[q][p][2] = acc2;
    sm[q][p][3] = acc3; sm[q][p][4] = acc4;
    __syncthreads();

    if (t < 64) {
        double Ss = 0, So = 0, Sss = 0, Soo = 0, Sso = 0;
        #pragma unroll
        for (int qq = 0; qq < 4; ++qq) {
            Ss  += sm[qq][p][0];
            So  += sm[qq][p][1];
            Sss += sm[qq][p][2];
            Soo += sm[qq][p][3];
            Sso += sm[qq][p][4];
        }
        const double N = (double)PLANE_ELEMS;
        double cross = Sso - Ss * So / N;
        double Ep    = Sss - Ss * Ss / N;
        double Et    = Soo - So * So / N;
        double term  = cross / (sqrt(Et) * sqrt(Ep));

        #pragma unroll
        for (int off = 32; off > 0; off >>= 1)
            term += __shfl_down(term, off);

        if (p == 0)
            out[0] = (float)(-term);
    }
}

extern "C" void kernel_launch(void* const* d_in, const int* in_sizes, int n_in,
                              void* d_out, int out_size, void* d_ws, size_t ws_size,
                              hipStream_t stream)
{
    const float* syn = (const float*)d_in[0];
    const float* obs = (const float*)d_in[1];
    float* out       = (float*)d_out;
    double* ws       = (double*)d_ws;

    fwi_partials<<<NPLANES * BPP, THREADS, 0, stream>>>(syn, obs, ws);
    fwi_final<<<1, 256, 0, stream>>>(ws, out);
}

// Round 4
// 135.358 us; speedup vs baseline: 1.1506x; 1.0035x over previous
//
#include <hip/hip_runtime.h>
#include <math.h>

// Problem geometry (fixed by the reference): (4,16,4000,400) fp32
#define PLANE_ELEMS 1600000            // 4000*400 per (batch,shot) plane
#define NPLANES     64                 // 4*16
#define BPP         32                 // blocks per plane
#define THREADS     256                // threads per block (4 waves)
#define N4          (PLANE_ELEMS / 4)  // 400000 float4 per plane
#define CHUNK       (N4 / BPP)         // 12500 float4 per block (contiguous)
#define UNROLL      4
#define NROUND      (CHUNK / (THREADS * UNROLL))  // 12 full rounds
#define TAILBASE    (NROUND * THREADS * UNROLL)   // 12288 (tail = 212)

typedef float f32x4 __attribute__((ext_vector_type(4)));

// Stage 1: per-plane raw moments. Full-chunk f32 VECTOR accumulation
// (20 independent FMA chains, ~60 VGPR -> full occupancy), f64 only at
// the wave reduce. Nontemporal streaming loads.
// ws layout: ws[(plane*BPP + bip)*5 + {0:S_s, 1:S_o, 2:S_ss, 3:S_oo, 4:S_so}]
__global__ __launch_bounds__(THREADS)
void fwi_partials(const float* __restrict__ syn,
                  const float* __restrict__ obs,
                  double* __restrict__ ws)
{
    const int plane = blockIdx.x >> 5;      // / BPP
    const int bip   = blockIdx.x & (BPP - 1);

    const f32x4* s4 = reinterpret_cast<const f32x4*>(syn)
                      + (size_t)plane * N4 + (size_t)bip * CHUNK;
    const f32x4* o4 = reinterpret_cast<const f32x4*>(obs)
                      + (size_t)plane * N4 + (size_t)bip * CHUNK;

    f32x4 vs  = {0.f, 0.f, 0.f, 0.f};
    f32x4 vo  = {0.f, 0.f, 0.f, 0.f};
    f32x4 vss = {0.f, 0.f, 0.f, 0.f};
    f32x4 voo = {0.f, 0.f, 0.f, 0.f};
    f32x4 vso = {0.f, 0.f, 0.f, 0.f};

    int i = threadIdx.x;
    for (int r = 0; r < NROUND; ++r) {
        f32x4 a[UNROLL], b[UNROLL];
        #pragma unroll
        for (int u = 0; u < UNROLL; ++u) {
            a[u] = __builtin_nontemporal_load(s4 + i + u * THREADS);
            b[u] = __builtin_nontemporal_load(o4 + i + u * THREADS);
        }
        #pragma unroll
        for (int u = 0; u < UNROLL; ++u) {
            vs  += a[u];
            vo  += b[u];
            vss = __builtin_elementwise_fma(a[u], a[u], vss);
            voo = __builtin_elementwise_fma(b[u], b[u], voo);
            vso = __builtin_elementwise_fma(a[u], b[u], vso);
        }
        i += THREADS * UNROLL;
    }

    // Tail: CHUNK = 12500 = 12*1024 + 212; threads with tid < 212 do one more.
    i = TAILBASE + threadIdx.x;
    if (i < CHUNK) {
        f32x4 a = __builtin_nontemporal_load(s4 + i);
        f32x4 b = __builtin_nontemporal_load(o4 + i);
        vs  += a;
        vo  += b;
        vss = __builtin_elementwise_fma(a, a, vss);
        voo = __builtin_elementwise_fma(b, b, voo);
        vso = __builtin_elementwise_fma(a, b, vso);
    }

    // Horizontal reduce each vector accumulator in fp64
    double d_s  = ((double)vs.x  + (double)vs.y)  + ((double)vs.z  + (double)vs.w);
    double d_o  = ((double)vo.x  + (double)vo.y)  + ((double)vo.z  + (double)vo.w);
    double d_ss = ((double)vss.x + (double)vss.y) + ((double)vss.z + (double)vss.w);
    double d_oo = ((double)voo.x + (double)voo.y) + ((double)voo.z + (double)voo.w);
    double d_so = ((double)vso.x + (double)vso.y) + ((double)vso.z + (double)vso.w);

    // Wave(64)-level butterfly reduction in fp64
    #pragma unroll
    for (int off = 32; off > 0; off >>= 1) {
        d_s  += __shfl_down(d_s,  off);
        d_o  += __shfl_down(d_o,  off);
        d_ss += __shfl_down(d_ss, off);
        d_oo += __shfl_down(d_oo, off);
        d_so += __shfl_down(d_so, off);
    }

    __shared__ double sm[THREADS / 64][5];
    const int wave = threadIdx.x >> 6;
    const int lane = threadIdx.x & 63;
    if (lane == 0) {
        sm[wave][0] = d_s;  sm[wave][1] = d_o;
        sm[wave][2] = d_ss; sm[wave][3] = d_oo; sm[wave][4] = d_so;
    }
    __syncthreads();

    if (threadIdx.x == 0) {
        double t0 = 0, t1 = 0, t2 = 0, t3 = 0, t4 = 0;
        #pragma unroll
        for (int w = 0; w < THREADS / 64; ++w) {
            t0 += sm[w][0]; t1 += sm[w][1]; t2 += sm[w][2];
            t3 += sm[w][3]; t4 += sm[w][4];
        }
        double* r = ws + (size_t)blockIdx.x * 5;
        r[0] = t0; r[1] = t1; r[2] = t2; r[3] = t3; r[4] = t4;
    }
}

// Stage 2: one block of 256 threads reduces 64 planes x 32 partial records,
// computes the closed-form zero-mean correlation per plane, sums across planes.
__global__ __launch_bounds__(256)
void fwi_final(const double* __restrict__ ws, float* __restrict__ out)
{
    const int t = threadIdx.x;
    const int p = t & 63;        // plane
    const int q = t >> 6;        // quarter 0..3 (8 records each)

    double acc0 = 0, acc1 = 0, acc2 = 0, acc3 = 0, acc4 = 0;
    #pragma unroll
    for (int b = 0; b < BPP / 4; ++b) {
        const double* r = ws + (size_t)((p * BPP) + (q * (BPP / 4)) + b) * 5;
        acc0 += r[0]; acc1 += r[1]; acc2 += r[2]; acc3 += r[3]; acc4 += r[4];
    }

    __shared__ double sm[4][64][5];
    sm[q][p][0] = acc0; sm[q][p][1] = acc1; sm[q][p][2] = acc2;
    sm[q][p][3] = acc3; sm[q][p][4] = acc4;
    __syncthreads();

    if (t < 64) {
        double Ss = 0, So = 0, Sss = 0, Soo = 0, Sso = 0;
        #pragma unroll
        for (int qq = 0; qq < 4; ++qq) {
            Ss  += sm[qq][p][0];
            So  += sm[qq][p][1];
            Sss += sm[qq][p][2];
            Soo += sm[qq][p][3];
            Sso += sm[qq][p][4];
        }
        const double N = (double)PLANE_ELEMS;
        double cross = Sso - Ss * So / N;
        double Ep    = Sss - Ss * Ss / N;
        double Et    = Soo - So * So / N;
        double term  = cross / (sqrt(Et) * sqrt(Ep));

        #pragma unroll
        for (int off = 32; off > 0; off >>= 1)
            term += __shfl_down(term, off);

        if (p == 0)
            out[0] = (float)(-term);
    }
}

extern "C" void kernel_launch(void* const* d_in, const int* in_sizes, int n_in,
                              void* d_out, int out_size, void* d_ws, size_t ws_size,
                              hipStream_t stream)
{
    const float* syn = (const float*)d_in[0];
    const float* obs = (const float*)d_in[1];
    float* out       = (float*)d_out;
    double* ws       = (double*)d_ws;

    fwi_partials<<<NPLANES * BPP, THREADS, 0, stream>>>(syn, obs, ws);
    fwi_final<<<1, 256, 0, stream>>>(ws, out);
}